// Round 3
// baseline (2303.970 us; speedup 1.0000x reference)
//
#include <hip/hip_runtime.h>
#include <math.h>

#define BB 2048
#define LL 64
#define EE 200
#define HH 128
#define CDIM 128
#define VV 50000
#define G3 384    // 3H
#define PEW 768   // 2*3H
#define D2H 256   // 2H
#define EPSV 1e-5f

__device__ __forceinline__ float fast_sigmoid(float v) {
    return 1.f / (1.f + __expf(-v));
}
__device__ __forceinline__ float fast_tanh(float a) {
    float e = __expf(-2.f * fabsf(a));
    float m = (1.f - e) / (1.f + e);
    return copysignf(m, a);
}

// ---- bf16 (raw ushort) <-> f32 helpers; storage-dtype overloads ----
__device__ __forceinline__ float bf2f(unsigned short u) {
    union { unsigned int i; float f; } c; c.i = ((unsigned int)u) << 16; return c.f;
}
__device__ __forceinline__ unsigned short f2bf(float f) {
    union { float f; unsigned int i; } c; c.f = f;
    unsigned int r = c.i + 0x7FFF + ((c.i >> 16) & 1);   // round-nearest-even
    return (unsigned short)(r >> 16);
}
__device__ __forceinline__ float ldc(const float* p) { return *p; }
__device__ __forceinline__ float ldc(const unsigned short* p) { return bf2f(*p); }
__device__ __forceinline__ void stc(float* p, float v) { *p = v; }
__device__ __forceinline__ void stc(unsigned short* p, float v) { *p = f2bf(v); }
__device__ __forceinline__ float4 ld4(const float* p) { return *(const float4*)p; }
__device__ __forceinline__ float4 ld4(const unsigned short* p) {
    ushort4 u = *(const ushort4*)p;
    return make_float4(bf2f(u.x), bf2f(u.y), bf2f(u.z), bf2f(u.w));
}

// ---------------- K0: zero the BN stats accumulators ----------------
__global__ void zero_stats_kernel(float* __restrict__ stats) {
    if (threadIdx.x < 2 * LL) stats[threadIdx.x] = 0.f;
}

// ---------------- K1: projected-embedding table --------------------
// PE[v][0:384]   = Wih_f @ emb[v] + bih_f
// PE[v][384:768] = Wih_b @ emb[v] + bih_b
template <typename T>
__global__ __launch_bounds__(256) void pe_kernel(
    const float* __restrict__ emb,
    const float* __restrict__ Wih_f, const float* __restrict__ bih_f,
    const float* __restrict__ Wih_b, const float* __restrict__ bih_b,
    T* __restrict__ PE)
{
    __shared__ float At[64][8];
    __shared__ float Bt[64][8];
    const int mb = blockIdx.x * 64;
    const int nb = blockIdx.y * 64;            // 0..704, never straddles 384
    const float* W  = (nb < G3) ? Wih_f : Wih_b;
    const float* bi = (nb < G3) ? bih_f : bih_b;
    const int nloc  = (nb < G3) ? nb : nb - G3;
    const int t  = threadIdx.x;
    const int tr = t >> 4, tc = t & 15;
    float acc[4][4] = {};
    for (int k0 = 0; k0 < EE; k0 += 8) {
        #pragma unroll
        for (int i = 0; i < 2; ++i) {
            int idx = t * 2 + i;
            int r = idx >> 3, kk = idx & 7;
            int row = mb + r;
            At[r][kk] = (row < VV) ? emb[(size_t)row * EE + k0 + kk] : 0.f;
            Bt[r][kk] = W[(size_t)(nloc + r) * EE + k0 + kk];
        }
        __syncthreads();
        #pragma unroll
        for (int k = 0; k < 8; ++k) {
            float a[4], b[4];
            #pragma unroll
            for (int i = 0; i < 4; ++i) a[i] = At[tr * 4 + i][k];
            #pragma unroll
            for (int j = 0; j < 4; ++j) b[j] = Bt[tc * 4 + j][k];
            #pragma unroll
            for (int i = 0; i < 4; ++i)
                #pragma unroll
                for (int j = 0; j < 4; ++j)
                    acc[i][j] = fmaf(a[i], b[j], acc[i][j]);
        }
        __syncthreads();
    }
    #pragma unroll
    for (int i = 0; i < 4; ++i) {
        int row = mb + tr * 4 + i;
        if (row < VV) {
            #pragma unroll
            for (int j = 0; j < 4; ++j) {
                int col = nb + tc * 4 + j;
                stc(&PE[(size_t)row * PEW + col], acc[i][j] + bi[nloc + tc * 4 + j]);
            }
        }
    }
}

// ---------------- K1b: k-major float4 repack of a [R][K] matrix -----
__global__ void transpose4_kernel(const float* __restrict__ src,
                                  float* __restrict__ dst, int R, int K) {
    int idx = blockIdx.x * blockDim.x + threadIdx.x;  // float4 index
    int total = R * (K >> 2);
    if (idx >= total) return;
    int k4 = idx / R, r = idx - k4 * R;
    float4 v;
    v.x = src[r * K + k4 * 4 + 0];
    v.y = src[r * K + k4 * 4 + 1];
    v.z = src[r * K + k4 * 4 + 2];
    v.w = src[r * K + k4 * 4 + 3];
    ((float4*)dst)[idx] = v;
}

// ---------------- K2: bidirectional GRU recurrence ------------------
// 256 blocks = 2 dirs x 128 batch-tiles(16). 512 threads = 128 j x 4 st.
template <typename TPE, typename TOUT>
__global__ __launch_bounds__(512) void gru_kernel(
    const int* __restrict__ xw, const int* __restrict__ lens,
    const TPE* __restrict__ PE,
    const float* __restrict__ WT4_f, const float* __restrict__ bhh_f,
    const float* __restrict__ WT4_b, const float* __restrict__ bhh_b,
    TOUT* __restrict__ out)
{
    const int dir = blockIdx.x >> 7;
    const int b0  = (blockIdx.x & 127) * 16;
    const float4* WT4 = (const float4*)(dir ? WT4_b : WT4_f);
    const float* bhh  = dir ? bhh_b : bhh_f;
    const int t  = threadIdx.x;
    const int j  = t & 127;
    const int st = t >> 7;               // 0..3, owns samples st*4..st*4+3
    __shared__ float hsh[16][HH];
    __shared__ int   toks[16];
    for (int i = t; i < 16 * HH; i += 512) ((float*)hsh)[i] = 0.f;
    const float br = bhh[j], bz = bhh[HH + j], bn = bhh[2 * HH + j];
    const int peBase = dir * G3;
    __syncthreads();
    for (int step = 0; step < LL; ++step) {
        const int l = dir ? (LL - 1 - step) : step;
        if (t < 16) toks[t] = xw[(b0 + t) * LL + l];
        __syncthreads();
        float ar[4] = {}, az[4] = {}, an[4] = {};
        #pragma unroll 2
        for (int k4 = 0; k4 < (HH / 4); ++k4) {
            const float4 wr = WT4[k4 * G3 + j];
            const float4 wz = WT4[k4 * G3 + HH + j];
            const float4 wn = WT4[k4 * G3 + 2 * HH + j];
            #pragma unroll
            for (int i = 0; i < 4; ++i) {
                const int s = st * 4 + i;
                const float4 hv = *((const float4*)&hsh[s][k4 * 4]);
                ar[i] = fmaf(hv.x, wr.x, ar[i]); ar[i] = fmaf(hv.y, wr.y, ar[i]);
                ar[i] = fmaf(hv.z, wr.z, ar[i]); ar[i] = fmaf(hv.w, wr.w, ar[i]);
                az[i] = fmaf(hv.x, wz.x, az[i]); az[i] = fmaf(hv.y, wz.y, az[i]);
                az[i] = fmaf(hv.z, wz.z, az[i]); az[i] = fmaf(hv.w, wz.w, az[i]);
                an[i] = fmaf(hv.x, wn.x, an[i]); an[i] = fmaf(hv.y, wn.y, an[i]);
                an[i] = fmaf(hv.z, wn.z, an[i]); an[i] = fmaf(hv.w, wn.w, an[i]);
            }
        }
        __syncthreads();   // everyone done reading h
        #pragma unroll
        for (int i = 0; i < 4; ++i) {
            const int s   = st * 4 + i;
            const int tok = toks[s];
            const float xr = ldc(PE + (size_t)tok * PEW + peBase + j);
            const float xz = ldc(PE + (size_t)tok * PEW + peBase + HH + j);
            const float xn = ldc(PE + (size_t)tok * PEW + peBase + 2 * HH + j);
            const float hr = ar[i] + br, hz = az[i] + bz, hn = an[i] + bn;
            const float r = fast_sigmoid(xr + hr);
            const float z = fast_sigmoid(xz + hz);
            const float n = fast_tanh(xn + r * hn);
            const float hold = hsh[s][j];
            const float hnew = (1.f - z) * n + z * hold;
            hsh[s][j] = hnew;
            const int bb = b0 + s;
            stc(&out[((size_t)bb * LL + l) * D2H + dir * HH + j],
                (l < lens[bb]) ? hnew : 0.f);
        }
        __syncthreads();
    }
}

// ---------------- K3: projection GEMM + BN stats --------------------
template <typename TOUT>
__global__ __launch_bounds__(256) void proj_kernel(
    const TOUT* __restrict__ out, const float* __restrict__ WpT4,
    const float* __restrict__ bp,
    float* __restrict__ proj, float* __restrict__ stats)
{
    __shared__ float outs[32][D2H];   // 32 KB
    __shared__ float red[2][4];
    const int b0 = blockIdx.x * 32;
    const int l  = blockIdx.y;
    const int t  = threadIdx.x;
    for (int idx = t; idx < 32 * (D2H / 4); idx += 256) {
        int r = idx >> 6, c4 = idx & 63;
        float4 v = ld4(out + ((size_t)(b0 + r) * LL + l) * D2H + c4 * 4);
        *((float4*)&outs[r][c4 * 4]) = v;
    }
    __syncthreads();
    const int tr = t >> 5;   // 0..7 -> rows tr*4..tr*4+3
    const int tc = t & 31;   // cols tc*4..tc*4+3
    float acc[4][4] = {};
    for (int k4 = 0; k4 < D2H / 4; ++k4) {
        float4 w[4];
        #pragma unroll
        for (int jj = 0; jj < 4; ++jj)
            w[jj] = ((const float4*)WpT4)[k4 * CDIM + tc * 4 + jj];
        #pragma unroll
        for (int i = 0; i < 4; ++i) {
            float4 a = *((const float4*)&outs[tr * 4 + i][k4 * 4]);
            #pragma unroll
            for (int jj = 0; jj < 4; ++jj) {
                acc[i][jj] = fmaf(a.x, w[jj].x, acc[i][jj]);
                acc[i][jj] = fmaf(a.y, w[jj].y, acc[i][jj]);
                acc[i][jj] = fmaf(a.z, w[jj].z, acc[i][jj]);
                acc[i][jj] = fmaf(a.w, w[jj].w, acc[i][jj]);
            }
        }
    }
    float s1 = 0.f, s2 = 0.f;
    #pragma unroll
    for (int i = 0; i < 4; ++i) {
        int b = b0 + tr * 4 + i;
        float4 pv;
        #pragma unroll
        for (int jj = 0; jj < 4; ++jj) {
            float v = acc[i][jj] + bp[tc * 4 + jj];
            (&pv.x)[jj] = v;
            s1 += v; s2 += v * v;
        }
        *((float4*)(proj + ((size_t)b * LL + l) * CDIM + tc * 4)) = pv;
    }
    #pragma unroll
    for (int off = 32; off > 0; off >>= 1) {
        s1 += __shfl_down(s1, off);
        s2 += __shfl_down(s2, off);
    }
    const int lane = t & 63, w = t >> 6;
    if (lane == 0) { red[0][w] = s1; red[1][w] = s2; }
    __syncthreads();
    if (t == 0) {
        atomicAdd(&stats[l],      red[0][0] + red[0][1] + red[0][2] + red[0][3]);
        atomicAdd(&stats[LL + l], red[1][0] + red[1][1] + red[1][2] + red[1][3]);
    }
}

// ---------------- K4: BN apply + relu + dot with ctx ----------------
__global__ __launch_bounds__(256) void logits_kernel(
    const float* __restrict__ proj, const float* __restrict__ stats,
    const float* __restrict__ gamma, const float* __restrict__ beta,
    const float* __restrict__ ctx, float* __restrict__ logits)
{
    const int idx  = blockIdx.x * 4 + (threadIdx.x >> 6);  // (b,l)
    const int lane = threadIdx.x & 63;
    const int b = idx >> 6, l = idx & 63;
    const float invN = 1.f / (float)(BB * CDIM);
    const float mean = stats[l] * invN;
    const float var  = stats[LL + l] * invN - mean * mean;
    const float inv  = rsqrtf(var + EPSV);
    const float g = gamma[l], be = beta[l];
    const float2 p = ((const float2*)(proj + ((size_t)b * LL + l) * CDIM))[lane];
    const float2 c = ((const float2*)ctx)[lane];
    float v0 = fmaxf((p.x - mean) * inv * g + be, 0.f);
    float v1 = fmaxf((p.y - mean) * inv * g + be, 0.f);
    float s = v0 * c.x + v1 * c.y;
    #pragma unroll
    for (int off = 32; off > 0; off >>= 1) s += __shfl_down(s, off);
    if (lane == 0) logits[idx] = s;
}

// ---------------- K5: softmax over L + weighted sum -----------------
template <typename TOUT>
__global__ __launch_bounds__(256) void att_out_kernel(
    const TOUT* __restrict__ out, const float* __restrict__ logits,
    float* __restrict__ y)
{
    const int b = blockIdx.x;
    const int t = threadIdx.x;
    __shared__ float att[LL];
    if (t < 64) {
        float v = logits[b * LL + t];
        float m = v;
        #pragma unroll
        for (int off = 32; off > 0; off >>= 1) m = fmaxf(m, __shfl_xor(m, off));
        float e = __expf(v - m);
        float ssum = e;
        #pragma unroll
        for (int off = 32; off > 0; off >>= 1) ssum += __shfl_xor(ssum, off);
        att[t] = e / ssum;
    }
    __syncthreads();
    float acc = 0.f;
    const TOUT* ob = out + (size_t)b * LL * D2H + t;
    #pragma unroll
    for (int l = 0; l < LL; ++l) acc = fmaf(ldc(ob + (size_t)l * D2H), att[l], acc);
    y[b * D2H + t] = acc;
}

extern "C" void kernel_launch(void* const* d_in, const int* in_sizes, int n_in,
                              void* d_out, int out_size, void* d_ws, size_t ws_size,
                              hipStream_t stream) {
    const int*   xw     = (const int*)d_in[0];
    // d_in[1] word_hidden_stat: unused (reference uses fresh zeros)
    const int*   lens   = (const int*)d_in[2];
    const float* emb    = (const float*)d_in[3];
    const float* Wih_f  = (const float*)d_in[4];
    const float* Whh_f  = (const float*)d_in[5];
    const float* bih_f  = (const float*)d_in[6];
    const float* bhh_f  = (const float*)d_in[7];
    const float* Wih_b  = (const float*)d_in[8];
    const float* Whh_b  = (const float*)d_in[9];
    const float* bih_b  = (const float*)d_in[10];
    const float* bhh_b  = (const float*)d_in[11];
    const float* Wp     = (const float*)d_in[12];
    const float* bp     = (const float*)d_in[13];
    const float* gamma  = (const float*)d_in[14];
    const float* beta   = (const float*)d_in[15];
    const float* ctx    = (const float*)d_in[16];
    float* y = (float*)d_out;

    // ---- workspace layout (byte-based; adaptive precision to fit ws) ----
    char* base = (char*)d_ws;
    size_t off = 0;
    auto alloc = [&](size_t bytes) -> void* {
        void* p = base + off; off += (bytes + 255) & ~(size_t)255; return p;
    };
    // extras first (same for both plans)
    float* WT4f  = (float*)alloc((size_t)G3 * HH * 4);
    float* WT4b  = (float*)alloc((size_t)G3 * HH * 4);
    float* WpT4  = (float*)alloc((size_t)CDIM * D2H * 4);
    float* stats = (float*)alloc(2 * LL * 4);
    float* logit = (float*)alloc((size_t)BB * LL * 4);
    const size_t extras = off;
    const size_t peB_A  = (size_t)VV * PEW * 4;          // fp32 PE
    const size_t outB_A = (size_t)BB * LL * D2H * 4;     // fp32 out
    const size_t needA  = extras + peB_A + outB_A + 4096;
    const bool planA = ws_size >= needA;

    // common pre-passes
    zero_stats_kernel<<<1, 128, 0, stream>>>(stats);
    transpose4_kernel<<<(G3 * HH / 4 + 255) / 256, 256, 0, stream>>>(Whh_f, WT4f, G3, HH);
    transpose4_kernel<<<(G3 * HH / 4 + 255) / 256, 256, 0, stream>>>(Whh_b, WT4b, G3, HH);
    transpose4_kernel<<<(CDIM * D2H / 4 + 255) / 256, 256, 0, stream>>>(Wp, WpT4, CDIM, D2H);

    const dim3 peGrid((VV + 63) / 64, PEW / 64);
    if (planA) {
        float* PE   = (float*)alloc(peB_A);
        float* outb = (float*)alloc(outB_A);
        float* proj = (float*)PE;   // alias: PE dead after gru_kernel; 67MB <= 153.6MB
        pe_kernel<float><<<peGrid, 256, 0, stream>>>(emb, Wih_f, bih_f, Wih_b, bih_b, PE);
        gru_kernel<float, float><<<256, 512, 0, stream>>>(
            xw, lens, PE, WT4f, bhh_f, WT4b, bhh_b, outb);
        proj_kernel<float><<<dim3(BB / 32, LL), 256, 0, stream>>>(outb, WpT4, bp, proj, stats);
        logits_kernel<<<BB * LL / 4, 256, 0, stream>>>(proj, stats, gamma, beta, ctx, logit);
        att_out_kernel<float><<<BB, 256, 0, stream>>>(outb, logit, y);
    } else {
        // Plan C: bf16 storage for PE and out (math stays fp32). ~145 MB total.
        unsigned short* PE   = (unsigned short*)alloc((size_t)VV * PEW * 2);
        unsigned short* outb = (unsigned short*)alloc((size_t)BB * LL * D2H * 2);
        float* proj = (float*)PE;   // alias: 67MB fp32 <= 76.8MB bf16 PE region
        pe_kernel<unsigned short><<<peGrid, 256, 0, stream>>>(emb, Wih_f, bih_f, Wih_b, bih_b, PE);
        gru_kernel<unsigned short, unsigned short><<<256, 512, 0, stream>>>(
            xw, lens, PE, WT4f, bhh_f, WT4b, bhh_b, outb);
        proj_kernel<unsigned short><<<dim3(BB / 32, LL), 256, 0, stream>>>(outb, WpT4, bp, proj, stats);
        logits_kernel<<<BB * LL / 4, 256, 0, stream>>>(proj, stats, gamma, beta, ctx, logit);
        att_out_kernel<unsigned short><<<BB, 256, 0, stream>>>(outb, logit, y);
    }
}

// Round 5
// 994.056 us; speedup vs baseline: 2.3177x; 2.3177x over previous
//
#include <hip/hip_runtime.h>
#include <math.h>

#define BB 2048
#define LL 64
#define EE 200
#define HH 128
#define CDIM 128
#define VV 50000
#define G3 384    // 3H
#define PEW 768   // 2*3H
#define D2H 256   // 2H
#define EPSV 1e-5f

__device__ __forceinline__ float fast_sigmoid(float v) {
    return 1.f / (1.f + __expf(-v));
}
__device__ __forceinline__ float fast_tanh(float a) {
    float e = __expf(-2.f * fabsf(a));
    float m = (1.f - e) / (1.f + e);
    return copysignf(m, a);
}

// ---- bf16 (raw ushort) <-> f32 helpers; storage-dtype overloads ----
__device__ __forceinline__ float bf2f(unsigned short u) {
    union { unsigned int i; float f; } c; c.i = ((unsigned int)u) << 16; return c.f;
}
__device__ __forceinline__ unsigned short f2bf(float f) {
    union { float f; unsigned int i; } c; c.f = f;
    unsigned int r = c.i + 0x7FFF + ((c.i >> 16) & 1);   // round-nearest-even
    return (unsigned short)(r >> 16);
}
__device__ __forceinline__ float ldc(const float* p) { return *p; }
__device__ __forceinline__ float ldc(const unsigned short* p) { return bf2f(*p); }
__device__ __forceinline__ void stc(float* p, float v) { *p = v; }
__device__ __forceinline__ void stc(unsigned short* p, float v) { *p = f2bf(v); }
__device__ __forceinline__ float4 ld4(const float* p) { return *(const float4*)p; }
__device__ __forceinline__ float4 ld4(const unsigned short* p) {
    ushort4 u = *(const ushort4*)p;
    return make_float4(bf2f(u.x), bf2f(u.y), bf2f(u.z), bf2f(u.w));
}

// ---------------- K0: zero the BN stats accumulators ----------------
__global__ void zero_stats_kernel(float* __restrict__ stats) {
    if (threadIdx.x < 2 * LL) stats[threadIdx.x] = 0.f;
}

// ---------------- K1: projected-embedding table --------------------
// PE[v][0:384]   = Wih_f @ emb[v] + bih_f
// PE[v][384:768] = Wih_b @ emb[v] + bih_b
// 128x128 tile, 8x8/thread, k-major LDS with split fragments (bank-conflict-free).
template <typename T>
__global__ __launch_bounds__(256) void pe_kernel(
    const float* __restrict__ emb,
    const float* __restrict__ Wih_f, const float* __restrict__ bih_f,
    const float* __restrict__ Wih_b, const float* __restrict__ bih_b,
    T* __restrict__ PE)
{
    __shared__ float As[8][136];   // [k][row], pad 136 (mod32=8)
    __shared__ float Bs[8][136];   // [k][col]
    const int mb = blockIdx.x * 128;
    const int nb = blockIdx.y * 128;           // 0..640, never straddles 384
    const float* W  = (nb < G3) ? Wih_f : Wih_b;
    const float* bi = (nb < G3) ? bih_f : bih_b;
    const int nloc  = (nb < G3) ? nb : nb - G3;
    const int t  = threadIdx.x;
    const int tr = t >> 4, tc = t & 15;        // 16x16 thread grid
    const int r  = t >> 1, q = t & 1;          // loader mapping: row r, float4 q
    float acc[8][8] = {};
    for (int k0 = 0; k0 < EE; k0 += 8) {       // 25 exact iterations
        // stage loads to registers first
        float4 av, bv;
        const int arow = mb + r;
        if (arow < VV) av = *(const float4*)(emb + (size_t)arow * EE + k0 + q * 4);
        else           av = make_float4(0.f, 0.f, 0.f, 0.f);
        bv = *(const float4*)(W + (size_t)(nloc + r) * EE + k0 + q * 4);
        __syncthreads();   // previous iteration's LDS reads complete
        #pragma unroll
        for (int m = 0; m < 4; ++m) {
            As[q * 4 + m][r] = (&av.x)[m];     // 2-way bank (free)
            Bs[q * 4 + m][r] = (&bv.x)[m];
        }
        __syncthreads();
        #pragma unroll
        for (int k = 0; k < 8; ++k) {
            float4 a0 = *(const float4*)&As[k][tr * 4];
            float4 a1 = *(const float4*)&As[k][64 + tr * 4];
            float4 b0 = *(const float4*)&Bs[k][tc * 4];       // 64 consecutive words/wave -> free
            float4 b1 = *(const float4*)&Bs[k][64 + tc * 4];
            float a8[8] = {a0.x,a0.y,a0.z,a0.w,a1.x,a1.y,a1.z,a1.w};
            float b8[8] = {b0.x,b0.y,b0.z,b0.w,b1.x,b1.y,b1.z,b1.w};
            #pragma unroll
            for (int i = 0; i < 8; ++i)
                #pragma unroll
                for (int j = 0; j < 8; ++j)
                    acc[i][j] = fmaf(a8[i], b8[j], acc[i][j]);
        }
    }
    #pragma unroll
    for (int i = 0; i < 8; ++i) {
        const int rl  = (i < 4) ? (tr * 4 + i) : (64 + tr * 4 + i - 4);
        const int row = mb + rl;
        if (row >= VV) continue;
        #pragma unroll
        for (int j = 0; j < 8; ++j) {
            const int cl = (j < 4) ? (tc * 4 + j) : (64 + tc * 4 + j - 4);
            stc(&PE[(size_t)row * PEW + nb + cl], acc[i][j] + bi[nloc + cl]);
        }
    }
}

// ---------------- K1b: k-major float4 repack of a [R][K] matrix -----
__global__ void transpose4_kernel(const float* __restrict__ src,
                                  float* __restrict__ dst, int R, int K) {
    int idx = blockIdx.x * blockDim.x + threadIdx.x;  // float4 index
    int total = R * (K >> 2);
    if (idx >= total) return;
    int k4 = idx / R, r = idx - k4 * R;
    float4 v;
    v.x = src[r * K + k4 * 4 + 0];
    v.y = src[r * K + k4 * 4 + 1];
    v.z = src[r * K + k4 * 4 + 2];
    v.w = src[r * K + k4 * 4 + 3];
    ((float4*)dst)[idx] = v;
}

// ---------------- K2: bidirectional GRU recurrence ------------------
// 256 blocks = 2 dirs x 128 batch-tiles(16). 512 threads = 128 j x 4 st.
template <typename TPE, typename TOUT>
__global__ __launch_bounds__(512) void gru_kernel(
    const int* __restrict__ xw, const int* __restrict__ lens,
    const TPE* __restrict__ PE,
    const float* __restrict__ WT4_f, const float* __restrict__ bhh_f,
    const float* __restrict__ WT4_b, const float* __restrict__ bhh_b,
    TOUT* __restrict__ out)
{
    const int dir = blockIdx.x >> 7;
    const int b0  = (blockIdx.x & 127) * 16;
    const float4* WT4 = (const float4*)(dir ? WT4_b : WT4_f);
    const float* bhh  = dir ? bhh_b : bhh_f;
    const int t  = threadIdx.x;
    const int j  = t & 127;
    const int st = t >> 7;               // 0..3, owns samples st*4..st*4+3
    __shared__ float hsh[16][HH];
    __shared__ int   toks[16];
    for (int i = t; i < 16 * HH; i += 512) ((float*)hsh)[i] = 0.f;
    const float br = bhh[j], bz = bhh[HH + j], bn = bhh[2 * HH + j];
    const int peBase = dir * G3;
    __syncthreads();
    for (int step = 0; step < LL; ++step) {
        const int l = dir ? (LL - 1 - step) : step;
        if (t < 16) toks[t] = xw[(b0 + t) * LL + l];
        __syncthreads();
        float ar[4] = {}, az[4] = {}, an[4] = {};
        #pragma unroll 2
        for (int k4 = 0; k4 < (HH / 4); ++k4) {
            const float4 wr = WT4[k4 * G3 + j];
            const float4 wz = WT4[k4 * G3 + HH + j];
            const float4 wn = WT4[k4 * G3 + 2 * HH + j];
            #pragma unroll
            for (int i = 0; i < 4; ++i) {
                const int s = st * 4 + i;
                const float4 hv = *((const float4*)&hsh[s][k4 * 4]);
                ar[i] = fmaf(hv.x, wr.x, ar[i]); ar[i] = fmaf(hv.y, wr.y, ar[i]);
                ar[i] = fmaf(hv.z, wr.z, ar[i]); ar[i] = fmaf(hv.w, wr.w, ar[i]);
                az[i] = fmaf(hv.x, wz.x, az[i]); az[i] = fmaf(hv.y, wz.y, az[i]);
                az[i] = fmaf(hv.z, wz.z, az[i]); az[i] = fmaf(hv.w, wz.w, az[i]);
                an[i] = fmaf(hv.x, wn.x, an[i]); an[i] = fmaf(hv.y, wn.y, an[i]);
                an[i] = fmaf(hv.z, wn.z, an[i]); an[i] = fmaf(hv.w, wn.w, an[i]);
            }
        }
        __syncthreads();   // everyone done reading h
        #pragma unroll
        for (int i = 0; i < 4; ++i) {
            const int s   = st * 4 + i;
            const int tok = toks[s];
            const float xr = ldc(PE + (size_t)tok * PEW + peBase + j);
            const float xz = ldc(PE + (size_t)tok * PEW + peBase + HH + j);
            const float xn = ldc(PE + (size_t)tok * PEW + peBase + 2 * HH + j);
            const float hr = ar[i] + br, hz = az[i] + bz, hn = an[i] + bn;
            const float r = fast_sigmoid(xr + hr);
            const float z = fast_sigmoid(xz + hz);
            const float n = fast_tanh(xn + r * hn);
            const float hold = hsh[s][j];
            const float hnew = (1.f - z) * n + z * hold;
            hsh[s][j] = hnew;
            const int bb = b0 + s;
            stc(&out[((size_t)bb * LL + l) * D2H + dir * HH + j],
                (l < lens[bb]) ? hnew : 0.f);
        }
        __syncthreads();
    }
}

// ---------------- K3: projection GEMM + BN stats --------------------
template <typename TOUT>
__global__ __launch_bounds__(256) void proj_kernel(
    const TOUT* __restrict__ out, const float* __restrict__ WpT4,
    const float* __restrict__ bp,
    float* __restrict__ proj, float* __restrict__ stats)
{
    __shared__ float outs[32][D2H];   // 32 KB
    __shared__ float red[2][4];
    const int b0 = blockIdx.x * 32;
    const int l  = blockIdx.y;
    const int t  = threadIdx.x;
    for (int idx = t; idx < 32 * (D2H / 4); idx += 256) {
        int r = idx >> 6, c4 = idx & 63;
        float4 v = ld4(out + ((size_t)(b0 + r) * LL + l) * D2H + c4 * 4);
        *((float4*)&outs[r][c4 * 4]) = v;
    }
    __syncthreads();
    const int tr = t >> 5;   // 0..7 -> rows tr*4..tr*4+3
    const int tc = t & 31;   // cols tc*4..tc*4+3
    float acc[4][4] = {};
    for (int k4 = 0; k4 < D2H / 4; ++k4) {
        float4 w[4];
        #pragma unroll
        for (int jj = 0; jj < 4; ++jj)
            w[jj] = ((const float4*)WpT4)[k4 * CDIM + tc * 4 + jj];
        #pragma unroll
        for (int i = 0; i < 4; ++i) {
            float4 a = *((const float4*)&outs[tr * 4 + i][k4 * 4]);
            #pragma unroll
            for (int jj = 0; jj < 4; ++jj) {
                acc[i][jj] = fmaf(a.x, w[jj].x, acc[i][jj]);
                acc[i][jj] = fmaf(a.y, w[jj].y, acc[i][jj]);
                acc[i][jj] = fmaf(a.z, w[jj].z, acc[i][jj]);
                acc[i][jj] = fmaf(a.w, w[jj].w, acc[i][jj]);
            }
        }
    }
    float s1 = 0.f, s2 = 0.f;
    #pragma unroll
    for (int i = 0; i < 4; ++i) {
        int b = b0 + tr * 4 + i;
        float4 pv;
        #pragma unroll
        for (int jj = 0; jj < 4; ++jj) {
            float v = acc[i][jj] + bp[tc * 4 + jj];
            (&pv.x)[jj] = v;
            s1 += v; s2 += v * v;
        }
        *((float4*)(proj + ((size_t)b * LL + l) * CDIM + tc * 4)) = pv;
    }
    #pragma unroll
    for (int off = 32; off > 0; off >>= 1) {
        s1 += __shfl_down(s1, off);
        s2 += __shfl_down(s2, off);
    }
    const int lane = t & 63, w = t >> 6;
    if (lane == 0) { red[0][w] = s1; red[1][w] = s2; }
    __syncthreads();
    if (t == 0) {
        atomicAdd(&stats[l],      red[0][0] + red[0][1] + red[0][2] + red[0][3]);
        atomicAdd(&stats[LL + l], red[1][0] + red[1][1] + red[1][2] + red[1][3]);
    }
}

// ---------------- K4: BN apply + relu + dot with ctx ----------------
__global__ __launch_bounds__(256) void logits_kernel(
    const float* __restrict__ proj, const float* __restrict__ stats,
    const float* __restrict__ gamma, const float* __restrict__ beta,
    const float* __restrict__ ctx, float* __restrict__ logits)
{
    const int idx  = blockIdx.x * 4 + (threadIdx.x >> 6);  // (b,l)
    const int lane = threadIdx.x & 63;
    const int b = idx >> 6, l = idx & 63;
    const float invN = 1.f / (float)(BB * CDIM);
    const float mean = stats[l] * invN;
    const float var  = stats[LL + l] * invN - mean * mean;
    const float inv  = rsqrtf(var + EPSV);
    const float g = gamma[l], be = beta[l];
    const float2 p = ((const float2*)(proj + ((size_t)b * LL + l) * CDIM))[lane];
    const float2 c = ((const float2*)ctx)[lane];
    float v0 = fmaxf((p.x - mean) * inv * g + be, 0.f);
    float v1 = fmaxf((p.y - mean) * inv * g + be, 0.f);
    float s = v0 * c.x + v1 * c.y;
    #pragma unroll
    for (int off = 32; off > 0; off >>= 1) s += __shfl_down(s, off);
    if (lane == 0) logits[idx] = s;
}

// ---------------- K5: softmax over L + weighted sum -----------------
template <typename TOUT>
__global__ __launch_bounds__(256) void att_out_kernel(
    const TOUT* __restrict__ out, const float* __restrict__ logits,
    float* __restrict__ y)
{
    const int b = blockIdx.x;
    const int t = threadIdx.x;
    __shared__ float att[LL];
    if (t < 64) {
        float v = logits[b * LL + t];
        float m = v;
        #pragma unroll
        for (int off = 32; off > 0; off >>= 1) m = fmaxf(m, __shfl_xor(m, off));
        float e = __expf(v - m);
        float ssum = e;
        #pragma unroll
        for (int off = 32; off > 0; off >>= 1) ssum += __shfl_xor(ssum, off);
        att[t] = e / ssum;
    }
    __syncthreads();
    float acc = 0.f;
    const TOUT* ob = out + (size_t)b * LL * D2H + t;
    #pragma unroll
    for (int l = 0; l < LL; ++l) acc = fmaf(ldc(ob + (size_t)l * D2H), att[l], acc);
    y[b * D2H + t] = acc;
}

extern "C" void kernel_launch(void* const* d_in, const int* in_sizes, int n_in,
                              void* d_out, int out_size, void* d_ws, size_t ws_size,
                              hipStream_t stream) {
    const int*   xw     = (const int*)d_in[0];
    // d_in[1] word_hidden_stat: unused (reference uses fresh zeros)
    const int*   lens   = (const int*)d_in[2];
    const float* emb    = (const float*)d_in[3];
    const float* Wih_f  = (const float*)d_in[4];
    const float* Whh_f  = (const float*)d_in[5];
    const float* bih_f  = (const float*)d_in[6];
    const float* bhh_f  = (const float*)d_in[7];
    const float* Wih_b  = (const float*)d_in[8];
    const float* Whh_b  = (const float*)d_in[9];
    const float* bih_b  = (const float*)d_in[10];
    const float* bhh_b  = (const float*)d_in[11];
    const float* Wp     = (const float*)d_in[12];
    const float* bp     = (const float*)d_in[13];
    const float* gamma  = (const float*)d_in[14];
    const float* beta   = (const float*)d_in[15];
    const float* ctx    = (const float*)d_in[16];
    float* y = (float*)d_out;

    // ---- workspace layout (byte-based; adaptive precision to fit ws) ----
    char* base = (char*)d_ws;
    size_t off = 0;
    auto alloc = [&](size_t bytes) -> void* {
        void* p = base + off; off += (bytes + 255) & ~(size_t)255; return p;
    };
    // extras first (same for both plans)
    float* WT4f  = (float*)alloc((size_t)G3 * HH * 4);
    float* WT4b  = (float*)alloc((size_t)G3 * HH * 4);
    float* WpT4  = (float*)alloc((size_t)CDIM * D2H * 4);
    float* stats = (float*)alloc(2 * LL * 4);
    float* logit = (float*)alloc((size_t)BB * LL * 4);
    const size_t extras = off;
    const size_t peB_A  = (size_t)VV * PEW * 4;          // fp32 PE
    const size_t outB_A = (size_t)BB * LL * D2H * 4;     // fp32 out
    const size_t needA  = extras + peB_A + outB_A + 4096;
    const bool planA = ws_size >= needA;

    // common pre-passes
    zero_stats_kernel<<<1, 128, 0, stream>>>(stats);
    transpose4_kernel<<<(G3 * HH / 4 + 255) / 256, 256, 0, stream>>>(Whh_f, WT4f, G3, HH);
    transpose4_kernel<<<(G3 * HH / 4 + 255) / 256, 256, 0, stream>>>(Whh_b, WT4b, G3, HH);
    transpose4_kernel<<<(CDIM * D2H / 4 + 255) / 256, 256, 0, stream>>>(Wp, WpT4, CDIM, D2H);

    const dim3 peGrid((VV + 127) / 128, PEW / 128);
    if (planA) {
        float* PE   = (float*)alloc(peB_A);
        float* outb = (float*)alloc(outB_A);
        float* proj = (float*)PE;   // alias: PE dead after gru_kernel
        pe_kernel<float><<<peGrid, 256, 0, stream>>>(emb, Wih_f, bih_f, Wih_b, bih_b, PE);
        gru_kernel<float, float><<<256, 512, 0, stream>>>(
            xw, lens, PE, WT4f, bhh_f, WT4b, bhh_b, outb);
        proj_kernel<float><<<dim3(BB / 32, LL), 256, 0, stream>>>(outb, WpT4, bp, proj, stats);
        logits_kernel<<<BB * LL / 4, 256, 0, stream>>>(proj, stats, gamma, beta, ctx, logit);
        att_out_kernel<float><<<BB, 256, 0, stream>>>(outb, logit, y);
    } else {
        // Plan C: bf16 storage for PE and out (math stays fp32). ~145 MB total.
        unsigned short* PE   = (unsigned short*)alloc((size_t)VV * PEW * 2);
        unsigned short* outb = (unsigned short*)alloc((size_t)BB * LL * D2H * 2);
        float* proj = (float*)PE;   // alias: 67MB fp32 <= 76.8MB bf16 PE region
        pe_kernel<unsigned short><<<peGrid, 256, 0, stream>>>(emb, Wih_f, bih_f, Wih_b, bih_b, PE);
        gru_kernel<unsigned short, unsigned short><<<256, 512, 0, stream>>>(
            xw, lens, PE, WT4f, bhh_f, WT4b, bhh_b, outb);
        proj_kernel<unsigned short><<<dim3(BB / 32, LL), 256, 0, stream>>>(outb, WpT4, bp, proj, stats);
        logits_kernel<<<BB * LL / 4, 256, 0, stream>>>(proj, stats, gamma, beta, ctx, logit);
        att_out_kernel<unsigned short><<<BB, 256, 0, stream>>>(outb, logit, y);
    }
}